// Round 13
// baseline (203.594 us; speedup 1.0000x reference)
//
#include <hip/hip_runtime.h>
#include <hip/hip_fp16.h>

#define NNODES 100000
#define NEG_SLOPE 0.2f
#define NBK 49          // coarse buckets of 2048 nodes (dst>>11)
#define BKSHIFT 11
#define BKMASK 2047
#define BCAP 35328      // be[] slots/bucket; mean 32768, ~14 sigma slack
#define B1 4096         // edges per bin block
#define SLSTRIDE 56     // 56 % 8 == 0: slices of bucket B share blockIdx%8 == B%8

typedef _Float16 f16x8 __attribute__((ext_vector_type(8)));
typedef float f32x4 __attribute__((ext_vector_type(4)));

#if __has_builtin(__builtin_amdgcn_fdot2) && __has_builtin(__builtin_amdgcn_perm)
#define USE_DOT2 1
// cvt_pkrtz returns __fp16x2 on this toolchain; use its own type everywhere.
typedef decltype(__builtin_amdgcn_cvt_pkrtz(0.f, 0.f)) pk16x2;
#else
#define USE_DOT2 0
#endif

// ---------------- init ----------------

__global__ void k_init(int* __restrict__ gcur, int* __restrict__ offs, int N, int E) {
    int t = threadIdx.x;
    if (t < NBK) gcur[t] = t * BCAP;
    if (t == NBK) offs[N] = E;
}

// ---------------- fused: bin (blocks 0..390) + GEMM1 (rest) ----------------

__global__ __launch_bounds__(256, 4) void k_gemm1b(
    const float* __restrict__ x, const float* __restrict__ W,
    const float* __restrict__ al, const float* __restrict__ ar,
    __half* __restrict__ h, float* __restrict__ el, float* __restrict__ er,
    int N, int nbBin,
    const int* __restrict__ src, const int* __restrict__ dst,
    int* __restrict__ gcur, int* __restrict__ be, int E) {

    __shared__ float4 SMEM[2048];   // 32KB (gemm tiles)
    __shared__ int lcnt[NBK], lbase[NBK], lcur[NBK];
    int t = threadIdx.x;

    if ((int)blockIdx.x < nbBin) {  // ---- bin role ----
        int base = (int)blockIdx.x * B1;
        if (t < NBK) lcnt[t] = 0;
        __syncthreads();
        int dreg[16];
#pragma unroll
        for (int j = 0; j < 16; ++j) {
            int e = base + j * 256 + t;
            dreg[j] = (e < E) ? dst[e] : -1;
            if (e < E) atomicAdd(&lcnt[dreg[j] >> BKSHIFT], 1);
        }
        __syncthreads();
        if (t < NBK) { lbase[t] = atomicAdd(&gcur[t], lcnt[t]); lcur[t] = 0; }
        __syncthreads();
#pragma unroll
        for (int j = 0; j < 16; ++j) {
            int e = base + j * 256 + t;
            if (e < E) {
                int d = dreg[j];
                int bk = d >> BKSHIFT;
                int p = lbase[bk] + atomicAdd(&lcur[bk], 1);
                be[p] = (src[e] << BKSHIFT) | (d & BKMASK);
            }
        }
        return;
    }

    // ---- GEMM role ----
    char* A  = (char*)SMEM;          // 16KB: 64 rows x 256B f16 swz
    char* Bw = (char*)SMEM + 16384;  // 16KB: 64 cols x 256B f16 swz
    int row0 = ((int)blockIdx.x - nbBin) * 64;

    for (int i = t; i < 2048; i += 256) {
        int r = i >> 5, c4 = i & 31;
        int rr = row0 + r; if (rr > N - 1) rr = N - 1;
        float4 v = *(const float4*)(x + (size_t)rr * 128 + c4 * 4);
        int byte = r * 256 + ((c4 * 8) ^ ((r & 7) << 4));
        *(__half2*)(A + byte)     = __floats2half2_rn(v.x, v.y);
        *(__half2*)(A + byte + 4) = __floats2half2_rn(v.z, v.w);
    }
    for (int i = t; i < 2048; i += 256) {
        int k = i >> 4, c4 = (i & 15) * 4;
        float4 v = *(const float4*)(W + k * 64 + c4);
        int kb = k * 2;
        *(__half*)(Bw + (c4 + 0) * 256 + (kb ^ (((c4 + 0) & 7) << 4))) = __float2half(v.x);
        *(__half*)(Bw + (c4 + 1) * 256 + (kb ^ (((c4 + 1) & 7) << 4))) = __float2half(v.y);
        *(__half*)(Bw + (c4 + 2) * 256 + (kb ^ (((c4 + 2) & 7) << 4))) = __float2half(v.z);
        *(__half*)(Bw + (c4 + 3) * 256 + (kb ^ (((c4 + 3) & 7) << 4))) = __float2half(v.w);
    }
    __syncthreads();

    int w = t >> 6, l = t & 63, g = l >> 4, c = l & 15;
    int swz = (c & 7) << 4;
    const char* Ar = A + (w * 16 + c) * 256;

    f32x4 acc[4];
#pragma unroll
    for (int t2 = 0; t2 < 4; ++t2) acc[t2] = (f32x4){0.f, 0.f, 0.f, 0.f};
#pragma unroll
    for (int kk = 0; kk < 4; ++kk) {
        int kb = kk * 64 + g * 16;
        f16x8 av = *(const f16x8*)(Ar + (kb ^ swz));
#pragma unroll
        for (int t2 = 0; t2 < 4; ++t2) {
            f16x8 bv = *(const f16x8*)(Bw + (t2 * 16 + c) * 256 + (kb ^ swz));
            acc[t2] = __builtin_amdgcn_mfma_f32_16x16x32_f16(av, bv, acc[t2], 0, 0, 0);
        }
    }

    float alv[4], arv[4];
#pragma unroll
    for (int t2 = 0; t2 < 4; ++t2) { alv[t2] = al[t2 * 16 + c]; arv[t2] = ar[t2 * 16 + c]; }
#pragma unroll
    for (int r = 0; r < 4; ++r) {
        float e1 = 0.f, e2 = 0.f;
#pragma unroll
        for (int t2 = 0; t2 < 4; ++t2) {
            e1 = fmaf(acc[t2][r], alv[t2], e1);
            e2 = fmaf(acc[t2][r], arv[t2], e2);
        }
#pragma unroll
        for (int o = 1; o < 16; o <<= 1) { e1 += __shfl_xor(e1, o); e2 += __shfl_xor(e2, o); }
        int row = row0 + w * 16 + 4 * g + r;
        if (row < N) {
            if (c == 0) { el[row] = e1; er[row] = e2; }
#pragma unroll
            for (int t2 = 0; t2 < 4; ++t2)
                h[(size_t)row * 64 + t2 * 16 + c] = __float2half(acc[t2][r]);
        }
    }
}

// ---------------- offs: per-bucket node histogram + scan -> offs[] ----------

__global__ __launch_bounds__(256) void k_offs(const int* __restrict__ be,
                                              const int* __restrict__ gcur,
                                              int* __restrict__ offs, int N) {
    __shared__ int cnt[2048];
    __shared__ int sb[2][256];
    __shared__ int rbeg;
    int B = blockIdx.x, t = threadIdx.x;
    int mycnt = gcur[B] - B * BCAP;
    int ebase = B * BCAP;

    for (int i = t; i < 2048; i += 256) cnt[i] = 0;
    if (t == 0) rbeg = 0;
    __syncthreads();
    for (int i = t; i < mycnt; i += 256) atomicAdd(&cnt[be[ebase + i] & BKMASK], 1);
    if (t < 64) {
        int v = (t < B) ? gcur[t] - t * BCAP : 0;
#pragma unroll
        for (int o = 32; o; o >>= 1) v += __shfl_xor(v, o);
        if (t == 0) rbeg = v;
    }
    __syncthreads();

    int loc[8], s = 0;
#pragma unroll
    for (int i = 0; i < 8; ++i) { loc[i] = s; s += cnt[8 * t + i]; }
    sb[0][t] = s;
    __syncthreads();
    int pi = 0;
    for (int d = 1; d < 256; d <<= 1) {
        int po = pi ^ 1;
        sb[po][t] = sb[pi][t] + (t >= d ? sb[pi][t - d] : 0);
        pi = po;
        __syncthreads();
    }
    int bas = rbeg + sb[pi][t] - s;

    int node0 = (B << BKSHIFT) + 8 * t;
#pragma unroll
    for (int i = 0; i < 8; ++i) {
        int node = node0 + i;
        if (node < N) offs[node] = bas + loc[i];
    }
}

// ---------------- scatter slices with XCD affinity ----------------

__global__ __launch_bounds__(256) void k_scat(const int* __restrict__ be,
                                              const int* __restrict__ gcur,
                                              const int* __restrict__ offs,
                                              int* __restrict__ csr, int N) {
    int b = blockIdx.x;
    int B = b % SLSTRIDE, sl = b / SLSTRIDE;
    if (B >= NBK) return;

    __shared__ int cur[256];
    int t = threadIdx.x;
    int mycnt = gcur[B] - B * BCAP;
    int ebase = B * BCAP;
    int node = (B << BKSHIFT) + sl * 256 + t;
    cur[t] = (node < N) ? offs[node] : 0;
    __syncthreads();
    for (int i = t; i < mycnt; i += 256) {
        int v = be[ebase + i];
        int loc = v & BKMASK;
        if ((loc >> 8) == sl) {
            int p = atomicAdd(&cur[loc & 255], 1);
            csr[p] = v >> BKSHIFT;
        }
    }
}

// ---------------- agg core (one node per wave call) ----------------
// Inner loop uses v_dot2_f32_f16 (f32 accumulate): per 2 edges the two rows'
// same-feature halfs are interleaved with v_perm_b32 and alpha pairs packed
// with cvt_pkrtz -> ~30 VALU/quad vs 44 with cvt+fma (round 11: conversions
// were 36% of the loop). All shuffle trip counts wave-uniform (round-3 bug).

__device__ inline float2 h2_to_f2(float bits) {
    return __half22float2(__builtin_bit_cast(__half2, bits));
}

#if USE_DOT2
__device__ inline void edge_pair_dot(float2 r0, float2 r1, float w0, float w1,
                                     float4& accv) {
    unsigned a0 = __builtin_bit_cast(unsigned, r0.x);
    unsigned a1 = __builtin_bit_cast(unsigned, r0.y);
    unsigned b0 = __builtin_bit_cast(unsigned, r1.x);
    unsigned b1 = __builtin_bit_cast(unsigned, r1.y);
    pk16x2 wp = __builtin_amdgcn_cvt_pkrtz(w0, w1);
    unsigned p0 = __builtin_amdgcn_perm(b0, a0, 0x05040100u);  // (e0f0,e1f0)
    unsigned p1 = __builtin_amdgcn_perm(b0, a0, 0x07060302u);  // (e0f1,e1f1)
    unsigned p2 = __builtin_amdgcn_perm(b1, a1, 0x05040100u);  // (e0f2,e1f2)
    unsigned p3 = __builtin_amdgcn_perm(b1, a1, 0x07060302u);  // (e0f3,e1f3)
    accv.x = __builtin_amdgcn_fdot2(__builtin_bit_cast(pk16x2, p0), wp, accv.x, false);
    accv.y = __builtin_amdgcn_fdot2(__builtin_bit_cast(pk16x2, p1), wp, accv.y, false);
    accv.z = __builtin_amdgcn_fdot2(__builtin_bit_cast(pk16x2, p2), wp, accv.z, false);
    accv.w = __builtin_amdgcn_fdot2(__builtin_bit_cast(pk16x2, p3), wp, accv.w, false);
}
#endif

__device__ inline void edge_one(float2 r0, float w0, float4& accv) {
    float2 f00 = h2_to_f2(r0.x), f01 = h2_to_f2(r0.y);
    accv.x = fmaf(w0, f00.x, accv.x); accv.y = fmaf(w0, f00.y, accv.y);
    accv.z = fmaf(w0, f01.x, accv.z); accv.w = fmaf(w0, f01.y, accv.w);
}

__device__ float4 agg_node(const __half* __restrict__ h,
                           const float* __restrict__ el, float ern,
                           const int* __restrict__ csr_src,
                           int beg, int deg, int lane, int g, size_t foff) {
    float4 accv = make_float4(0.f, 0.f, 0.f, 0.f);

    if (deg <= 64) {
        int sidx = 0;
        float e = -1e30f;
        if (lane < deg) {
            sidx = csr_src[beg + lane];
            e = el[sidx] + ern;
            e = e > 0.f ? e : NEG_SLOPE * e;
        }
        float m = e;
#pragma unroll
        for (int o = 32; o; o >>= 1) m = fmaxf(m, __shfl_xor(m, o));
        float p = (lane < deg) ? __expf(e - m) : 0.f;
        float s = p;
#pragma unroll
        for (int o = 32; o; o >>= 1) s += __shfl_xor(s, o);
        float a = p * (1.f / fmaxf(s, 1e-9f));

        int iters = (deg + 3) >> 2;   // wave-uniform per-group trip count
        int quad = iters >> 2;
        int i = g;
        for (int t4 = 0; t4 < quad; ++t4, i += 16) {
            int s0 = __shfl(sidx, i),     s1 = __shfl(sidx, i + 4);
            int s2 = __shfl(sidx, i + 8), s3 = __shfl(sidx, i + 12);
            float w0 = __shfl(a, i),     w1 = __shfl(a, i + 4);
            float w2 = __shfl(a, i + 8), w3 = __shfl(a, i + 12);
            float2 r0 = *(const float2*)(h + (size_t)s0 * 64 + foff);
            float2 r1 = *(const float2*)(h + (size_t)s1 * 64 + foff);
            float2 r2 = *(const float2*)(h + (size_t)s2 * 64 + foff);
            float2 r3 = *(const float2*)(h + (size_t)s3 * 64 + foff);
#if USE_DOT2
            edge_pair_dot(r0, r1, w0, w1, accv);
            edge_pair_dot(r2, r3, w2, w3, accv);
#else
            edge_one(r0, w0, accv); edge_one(r1, w1, accv);
            edge_one(r2, w2, accv); edge_one(r3, w3, accv);
#endif
        }
        int rem = iters & 3;
        for (int rr2 = 0; rr2 < rem; ++rr2, i += 4) {
            int s0 = __shfl(sidx, i);
            float w0 = __shfl(a, i);
            float2 r0 = *(const float2*)(h + (size_t)s0 * 64 + foff);
            edge_one(r0, w0, accv);
        }
    } else {
        int end = beg + deg;
        float m = -1e30f;
        for (int i = beg + lane; i < end; i += 64) {
            float e = el[csr_src[i]] + ern;
            e = e > 0.f ? e : NEG_SLOPE * e;
            m = fmaxf(m, e);
        }
#pragma unroll
        for (int o = 32; o; o >>= 1) m = fmaxf(m, __shfl_xor(m, o));
        float s = 0.f;
        for (int i = beg + lane; i < end; i += 64) {
            float e = el[csr_src[i]] + ern;
            e = e > 0.f ? e : NEG_SLOPE * e;
            s += __expf(e - m);
        }
#pragma unroll
        for (int o = 32; o; o >>= 1) s += __shfl_xor(s, o);
        float inv = 1.f / fmaxf(s, 1e-9f);
        for (int i = g; i < deg; i += 4) {
            int s0 = csr_src[beg + i];
            float e = el[s0] + ern;
            e = e > 0.f ? e : NEG_SLOPE * e;
            float w0 = __expf(e - m) * inv;
            float2 r0 = *(const float2*)(h + (size_t)s0 * 64 + foff);
            edge_one(r0, w0, accv);
        }
    }

#pragma unroll
    for (int o = 16; o <= 32; o <<= 1) {
        accv.x += __shfl_xor(accv.x, o);
        accv.y += __shfl_xor(accv.y, o);
        accv.z += __shfl_xor(accv.z, o);
        accv.w += __shfl_xor(accv.w, o);
    }
    return accv;
}

// ---------------- fused agg1 + GEMM2 ----------------

__global__ __launch_bounds__(256, 4) void k_aggemm(
    const __half* __restrict__ h, const float* __restrict__ el,
    const float* __restrict__ er, const float* __restrict__ b1,
    const int* __restrict__ offs, const int* __restrict__ csr_src,
    const float* __restrict__ W2, const float* __restrict__ al2,
    const float* __restrict__ ar2,
    __half* __restrict__ h2, float* __restrict__ el2, float* __restrict__ er2,
    int N) {

    __shared__ float4 SMEM[1024];    // 16KB: A 8KB | W2t 8KB
    char* A  = (char*)SMEM;
    char* Bw = (char*)SMEM + 8192;
    int t = threadIdx.x;
    int w = t >> 6, lane = t & 63, g = lane >> 4, fl = lane & 15;
    int row0 = blockIdx.x * 64;

    // stage W2^T (64x64 f32 -> f16, swizzled)
    for (int i = t; i < 1024; i += 256) {
        int k = i >> 4, c4 = (i & 15) * 4;
        float4 v = *(const float4*)(W2 + k * 64 + c4);
        int kb = k * 2;
        *(__half*)(Bw + (c4 + 0) * 128 + (kb ^ (((c4 + 0) & 7) << 4))) = __float2half(v.x);
        *(__half*)(Bw + (c4 + 1) * 128 + (kb ^ (((c4 + 1) & 7) << 4))) = __float2half(v.y);
        *(__half*)(Bw + (c4 + 2) * 128 + (kb ^ (((c4 + 2) & 7) << 4))) = __float2half(v.z);
        *(__half*)(Bw + (c4 + 3) * 128 + (kb ^ (((c4 + 3) & 7) << 4))) = __float2half(v.w);
    }

    // ---- agg phase: wave w handles rows w*16 .. w*16+15 ----
    const size_t foff = 4 * (size_t)fl;
    float4 bv = *(const float4*)(b1 + foff);   // used by lanes 0..15
    for (int j = 0; j < 16; ++j) {
        int r = w * 16 + j;
        int n = row0 + r;
        int beg = 0, deg = 0;
        float ern = 0.f;
        if (n < N) {
            beg = offs[n];
            deg = offs[n + 1] - beg;
            ern = er[n];
        }
        float4 accv = agg_node(h, el, ern, csr_src, beg, deg, lane, g, foff);
        if (lane < 16) {
            float ox = fmaxf(accv.x + bv.x, 0.f);
            float oy = fmaxf(accv.y + bv.y, 0.f);
            float oz = fmaxf(accv.z + bv.z, 0.f);
            float ow = fmaxf(accv.w + bv.w, 0.f);
            __half2 h01 = __floats2half2_rn(ox, oy);
            __half2 h23 = __floats2half2_rn(oz, ow);
            float2 pk;
            pk.x = __builtin_bit_cast(float, h01);
            pk.y = __builtin_bit_cast(float, h23);
            *(float2*)(A + r * 128 + ((int)(fl * 8) ^ ((r & 7) << 4))) = pk;
        }
    }
    __syncthreads();

    // ---- MFMA phase (gemm2) ----
    int c = fl;
    int swz = (c & 7) << 4;
    const char* Ar = A + (w * 16 + c) * 128;

    f32x4 acc[4];
#pragma unroll
    for (int t2 = 0; t2 < 4; ++t2) acc[t2] = (f32x4){0.f, 0.f, 0.f, 0.f};
#pragma unroll
    for (int kk = 0; kk < 2; ++kk) {
        int kb = kk * 64 + g * 16;
        f16x8 av = *(const f16x8*)(Ar + (kb ^ swz));
#pragma unroll
        for (int t2 = 0; t2 < 4; ++t2) {
            f16x8 bvf = *(const f16x8*)(Bw + (t2 * 16 + c) * 128 + (kb ^ swz));
            acc[t2] = __builtin_amdgcn_mfma_f32_16x16x32_f16(av, bvf, acc[t2], 0, 0, 0);
        }
    }

    float alv[4], arv[4];
#pragma unroll
    for (int t2 = 0; t2 < 4; ++t2) { alv[t2] = al2[t2 * 16 + c]; arv[t2] = ar2[t2 * 16 + c]; }
#pragma unroll
    for (int r = 0; r < 4; ++r) {
        float e1 = 0.f, e2 = 0.f;
#pragma unroll
        for (int t2 = 0; t2 < 4; ++t2) {
            e1 = fmaf(acc[t2][r], alv[t2], e1);
            e2 = fmaf(acc[t2][r], arv[t2], e2);
        }
#pragma unroll
        for (int o = 1; o < 16; o <<= 1) { e1 += __shfl_xor(e1, o); e2 += __shfl_xor(e2, o); }
        int row = row0 + w * 16 + 4 * g + r;
        if (row < N) {
            if (c == 0) { el2[row] = e1; er2[row] = e2; }
#pragma unroll
            for (int t2 = 0; t2 < 4; ++t2)
                h2[(size_t)row * 64 + t2 * 16 + c] = __float2half(acc[t2][r]);
        }
    }
}

// ---------------- layer-2 agg (writes fp32 out) ----------------

__global__ __launch_bounds__(256) void k_agg2(const __half* __restrict__ h,
                                              const float* __restrict__ el,
                                              const float* __restrict__ er,
                                              const float* __restrict__ b,
                                              const int* __restrict__ offs,
                                              const int* __restrict__ csr_src,
                                              float* __restrict__ out, int N) {
    int wave = threadIdx.x >> 6, lane = threadIdx.x & 63;
    int n = blockIdx.x * 4 + wave;
    if (n >= N) return;

    int beg = offs[n], deg = offs[n + 1] - beg;
    int g = lane >> 4, fl = lane & 15;
    const size_t foff = 4 * (size_t)fl;

    float4 accv = agg_node(h, el, er[n], csr_src, beg, deg, lane, g, foff);

    if (lane < 16) {
        float4 bv = *(const float4*)(b + foff);
        *(float4*)(out + (size_t)n * 64 + foff) =
            make_float4(accv.x + bv.x, accv.y + bv.y, accv.z + bv.z, accv.w + bv.w);
    }
}

// ---------------- launch ----------------

extern "C" void kernel_launch(void* const* d_in, const int* in_sizes, int n_in,
                              void* d_out, int out_size, void* d_ws, size_t ws_size,
                              hipStream_t stream) {
    const float* x   = (const float*)d_in[0];
    const int*   src = (const int*)d_in[1];
    const int*   dst = (const int*)d_in[2];
    const float* W1  = (const float*)d_in[3];
    const float* al1 = (const float*)d_in[4];
    const float* ar1 = (const float*)d_in[5];
    const float* b1  = (const float*)d_in[6];
    const float* W2  = (const float*)d_in[7];
    const float* al2 = (const float*)d_in[8];
    const float* ar2 = (const float*)d_in[9];
    const float* b2  = (const float*)d_in[10];
    float* out = (float*)d_out;

    const int N = NNODES;
    const int E = in_sizes[1];

    __half* h    = (__half*)d_ws;                      // 12.8MB (layer-1 h)
    __half* h2   = h + (size_t)N * 64;                 // 12.8MB (layer-2 h)
    int*    be   = (int*)(h2 + (size_t)N * 64);        // NBK*BCAP (6.9MB)
    int*    csr  = be + (size_t)NBK * BCAP;            // E (6.4MB)
    float*  el   = (float*)(csr + E);                  // N
    float*  er   = el + N;                             // N
    float*  el2  = er + N;                             // N
    float*  er2  = el2 + N;                            // N
    int*    offs = (int*)(er2 + N);                    // N+1
    int*    gcur = offs + N + 1;                       // NBK

    int nbBin = (E + B1 - 1) / B1;            // 391
    int nbG   = (N + 63) / 64;                // 1563
    int nbR   = (N + 3) / 4;                  // 25000

    k_init<<<1, 64, 0, stream>>>(gcur, offs, N, E);
    // bin (391 blocks) fused with layer-1 MFMA GEMM (1563 blocks) - independent
    k_gemm1b<<<nbBin + nbG, 256, 0, stream>>>(x, W1, al1, ar1, h, el, er, N,
                                              nbBin, src, dst, gcur, be, E);
    k_offs<<<NBK, 256, 0, stream>>>(be, gcur, offs, N);
    k_scat<<<8 * SLSTRIDE, 256, 0, stream>>>(be, gcur, offs, csr, N);
    // fused: agg layer-1 + GEMM2 (hmid stays in LDS)
    k_aggemm<<<nbG, 256, 0, stream>>>(h, el, er, b1, offs, csr,
                                      W2, al2, ar2, h2, el2, er2, N);
    k_agg2<<<nbR, 256, 0, stream>>>(h2, el2, er2, b2, offs, csr, out, N);
}

// Round 14
// 202.993 us; speedup vs baseline: 1.0030x; 1.0030x over previous
//
#include <hip/hip_runtime.h>
#include <hip/hip_fp16.h>

#define NNODES 100000
#define NEG_SLOPE 0.2f
#define NBK 49          // coarse buckets of 2048 nodes (dst>>11)
#define BKSHIFT 11
#define BKMASK 2047
#define BCAP 35328      // be[] slots/bucket; mean 32768, ~14 sigma slack
#define B1 4096         // edges per bin block
#define SLSTRIDE 56     // 56 % 8 == 0: slices of bucket B share blockIdx%8 == B%8

typedef _Float16 f16x8 __attribute__((ext_vector_type(8)));
typedef float f32x4 __attribute__((ext_vector_type(4)));

#if __has_builtin(__builtin_amdgcn_fdot2) && __has_builtin(__builtin_amdgcn_perm)
#define USE_DOT2 1
typedef decltype(__builtin_amdgcn_cvt_pkrtz(0.f, 0.f)) pk16x2;
#else
#define USE_DOT2 0
#endif

// ---------------- init ----------------

__global__ void k_init(int* __restrict__ gcur, int* __restrict__ offs, int N, int E) {
    int t = threadIdx.x;
    if (t < NBK) gcur[t] = t * BCAP;
    if (t == NBK) offs[N] = E;
}

// ---------------- fused: bin (blocks 0..390) + GEMM1 (rest) ----------------
// launch_bounds (256,5): LDS 32KB caps at 5 blocks/CU; round 13 had 4.

__global__ __launch_bounds__(256, 5) void k_gemm1b(
    const float* __restrict__ x, const float* __restrict__ W,
    const float* __restrict__ al, const float* __restrict__ ar,
    __half* __restrict__ h, float* __restrict__ el, float* __restrict__ er,
    int N, int nbBin,
    const int* __restrict__ src, const int* __restrict__ dst,
    int* __restrict__ gcur, int* __restrict__ be, int E) {

    __shared__ float4 SMEM[2048];   // 32KB (gemm tiles)
    __shared__ int lcnt[NBK], lbase[NBK], lcur[NBK];
    int t = threadIdx.x;

    if ((int)blockIdx.x < nbBin) {  // ---- bin role ----
        int base = (int)blockIdx.x * B1;
        if (t < NBK) lcnt[t] = 0;
        __syncthreads();
        int dreg[16];
#pragma unroll
        for (int j = 0; j < 16; ++j) {
            int e = base + j * 256 + t;
            dreg[j] = (e < E) ? dst[e] : -1;
            if (e < E) atomicAdd(&lcnt[dreg[j] >> BKSHIFT], 1);
        }
        __syncthreads();
        if (t < NBK) { lbase[t] = atomicAdd(&gcur[t], lcnt[t]); lcur[t] = 0; }
        __syncthreads();
#pragma unroll
        for (int j = 0; j < 16; ++j) {
            int e = base + j * 256 + t;
            if (e < E) {
                int d = dreg[j];
                int bk = d >> BKSHIFT;
                int p = lbase[bk] + atomicAdd(&lcur[bk], 1);
                be[p] = (src[e] << BKSHIFT) | (d & BKMASK);
            }
        }
        return;
    }

    // ---- GEMM role ----
    char* A  = (char*)SMEM;          // 16KB: 64 rows x 256B f16 swz
    char* Bw = (char*)SMEM + 16384;  // 16KB: 64 cols x 256B f16 swz
    int row0 = ((int)blockIdx.x - nbBin) * 64;

    for (int i = t; i < 2048; i += 256) {
        int r = i >> 5, c4 = i & 31;
        int rr = row0 + r; if (rr > N - 1) rr = N - 1;
        float4 v = *(const float4*)(x + (size_t)rr * 128 + c4 * 4);
        int byte = r * 256 + ((c4 * 8) ^ ((r & 7) << 4));
        *(__half2*)(A + byte)     = __floats2half2_rn(v.x, v.y);
        *(__half2*)(A + byte + 4) = __floats2half2_rn(v.z, v.w);
    }
    for (int i = t; i < 2048; i += 256) {
        int k = i >> 4, c4 = (i & 15) * 4;
        float4 v = *(const float4*)(W + k * 64 + c4);
        int kb = k * 2;
        *(__half*)(Bw + (c4 + 0) * 256 + (kb ^ (((c4 + 0) & 7) << 4))) = __float2half(v.x);
        *(__half*)(Bw + (c4 + 1) * 256 + (kb ^ (((c4 + 1) & 7) << 4))) = __float2half(v.y);
        *(__half*)(Bw + (c4 + 2) * 256 + (kb ^ (((c4 + 2) & 7) << 4))) = __float2half(v.z);
        *(__half*)(Bw + (c4 + 3) * 256 + (kb ^ (((c4 + 3) & 7) << 4))) = __float2half(v.w);
    }
    __syncthreads();

    int w = t >> 6, l = t & 63, g = l >> 4, c = l & 15;
    int swz = (c & 7) << 4;
    const char* Ar = A + (w * 16 + c) * 256;

    f32x4 acc[4];
#pragma unroll
    for (int t2 = 0; t2 < 4; ++t2) acc[t2] = (f32x4){0.f, 0.f, 0.f, 0.f};
#pragma unroll
    for (int kk = 0; kk < 4; ++kk) {
        int kb = kk * 64 + g * 16;
        f16x8 av = *(const f16x8*)(Ar + (kb ^ swz));
#pragma unroll
        for (int t2 = 0; t2 < 4; ++t2) {
            f16x8 bv = *(const f16x8*)(Bw + (t2 * 16 + c) * 256 + (kb ^ swz));
            acc[t2] = __builtin_amdgcn_mfma_f32_16x16x32_f16(av, bv, acc[t2], 0, 0, 0);
        }
    }

    float alv[4], arv[4];
#pragma unroll
    for (int t2 = 0; t2 < 4; ++t2) { alv[t2] = al[t2 * 16 + c]; arv[t2] = ar[t2 * 16 + c]; }
#pragma unroll
    for (int r = 0; r < 4; ++r) {
        float e1 = 0.f, e2 = 0.f;
#pragma unroll
        for (int t2 = 0; t2 < 4; ++t2) {
            e1 = fmaf(acc[t2][r], alv[t2], e1);
            e2 = fmaf(acc[t2][r], arv[t2], e2);
        }
#pragma unroll
        for (int o = 1; o < 16; o <<= 1) { e1 += __shfl_xor(e1, o); e2 += __shfl_xor(e2, o); }
        int row = row0 + w * 16 + 4 * g + r;
        if (row < N) {
            if (c == 0) { el[row] = e1; er[row] = e2; }
#pragma unroll
            for (int t2 = 0; t2 < 4; ++t2)
                h[(size_t)row * 64 + t2 * 16 + c] = __float2half(acc[t2][r]);
        }
    }
}

// ---------------- offs: per-bucket node histogram + scan -> offs[] ----------

__global__ __launch_bounds__(256) void k_offs(const int* __restrict__ be,
                                              const int* __restrict__ gcur,
                                              int* __restrict__ offs, int N) {
    __shared__ int cnt[2048];
    __shared__ int sb[2][256];
    __shared__ int rbeg;
    int B = blockIdx.x, t = threadIdx.x;
    int mycnt = gcur[B] - B * BCAP;
    int ebase = B * BCAP;

    for (int i = t; i < 2048; i += 256) cnt[i] = 0;
    if (t == 0) rbeg = 0;
    __syncthreads();
    for (int i = t; i < mycnt; i += 256) atomicAdd(&cnt[be[ebase + i] & BKMASK], 1);
    if (t < 64) {
        int v = (t < B) ? gcur[t] - t * BCAP : 0;
#pragma unroll
        for (int o = 32; o; o >>= 1) v += __shfl_xor(v, o);
        if (t == 0) rbeg = v;
    }
    __syncthreads();

    int loc[8], s = 0;
#pragma unroll
    for (int i = 0; i < 8; ++i) { loc[i] = s; s += cnt[8 * t + i]; }
    sb[0][t] = s;
    __syncthreads();
    int pi = 0;
    for (int d = 1; d < 256; d <<= 1) {
        int po = pi ^ 1;
        sb[po][t] = sb[pi][t] + (t >= d ? sb[pi][t - d] : 0);
        pi = po;
        __syncthreads();
    }
    int bas = rbeg + sb[pi][t] - s;

    int node0 = (B << BKSHIFT) + 8 * t;
#pragma unroll
    for (int i = 0; i < 8; ++i) {
        int node = node0 + i;
        if (node < N) offs[node] = bas + loc[i];
    }
}

// ---------------- scatter slices with XCD affinity ----------------

__global__ __launch_bounds__(256) void k_scat(const int* __restrict__ be,
                                              const int* __restrict__ gcur,
                                              const int* __restrict__ offs,
                                              int* __restrict__ csr, int N) {
    int b = blockIdx.x;
    int B = b % SLSTRIDE, sl = b / SLSTRIDE;
    if (B >= NBK) return;

    __shared__ int cur[256];
    int t = threadIdx.x;
    int mycnt = gcur[B] - B * BCAP;
    int ebase = B * BCAP;
    int node = (B << BKSHIFT) + sl * 256 + t;
    cur[t] = (node < N) ? offs[node] : 0;
    __syncthreads();
    for (int i = t; i < mycnt; i += 256) {
        int v = be[ebase + i];
        int loc = v & BKMASK;
        if ((loc >> 8) == sl) {
            int p = atomicAdd(&cur[loc & 255], 1);
            csr[p] = v >> BKSHIFT;
        }
    }
}

// ---------------- agg core (one node per wave call) ----------------

__device__ inline float2 h2_to_f2(float bits) {
    return __half22float2(__builtin_bit_cast(__half2, bits));
}

#if USE_DOT2
__device__ inline void edge_pair_dot(float2 r0, float2 r1, float w0, float w1,
                                     float4& accv) {
    unsigned a0 = __builtin_bit_cast(unsigned, r0.x);
    unsigned a1 = __builtin_bit_cast(unsigned, r0.y);
    unsigned b0 = __builtin_bit_cast(unsigned, r1.x);
    unsigned b1 = __builtin_bit_cast(unsigned, r1.y);
    pk16x2 wp = __builtin_amdgcn_cvt_pkrtz(w0, w1);
    unsigned p0 = __builtin_amdgcn_perm(b0, a0, 0x05040100u);
    unsigned p1 = __builtin_amdgcn_perm(b0, a0, 0x07060302u);
    unsigned p2 = __builtin_amdgcn_perm(b1, a1, 0x05040100u);
    unsigned p3 = __builtin_amdgcn_perm(b1, a1, 0x07060302u);
    accv.x = __builtin_amdgcn_fdot2(__builtin_bit_cast(pk16x2, p0), wp, accv.x, false);
    accv.y = __builtin_amdgcn_fdot2(__builtin_bit_cast(pk16x2, p1), wp, accv.y, false);
    accv.z = __builtin_amdgcn_fdot2(__builtin_bit_cast(pk16x2, p2), wp, accv.z, false);
    accv.w = __builtin_amdgcn_fdot2(__builtin_bit_cast(pk16x2, p3), wp, accv.w, false);
}
#endif

__device__ inline void edge_one(float2 r0, float w0, float4& accv) {
    float2 f00 = h2_to_f2(r0.x), f01 = h2_to_f2(r0.y);
    accv.x = fmaf(w0, f00.x, accv.x); accv.y = fmaf(w0, f00.y, accv.y);
    accv.z = fmaf(w0, f01.x, accv.z); accv.w = fmaf(w0, f01.y, accv.w);
}

__device__ float4 agg_node(const __half* __restrict__ h,
                           const float* __restrict__ el, float ern,
                           const int* __restrict__ csr_src,
                           int beg, int deg, int lane, int g, size_t foff) {
    float4 accv = make_float4(0.f, 0.f, 0.f, 0.f);

    if (deg <= 64) {
        int sidx = 0;
        float e = -1e30f;
        if (lane < deg) {
            sidx = csr_src[beg + lane];
            e = el[sidx] + ern;
            e = e > 0.f ? e : NEG_SLOPE * e;
        }
        float m = e;
#pragma unroll
        for (int o = 32; o; o >>= 1) m = fmaxf(m, __shfl_xor(m, o));
        float p = (lane < deg) ? __expf(e - m) : 0.f;
        float s = p;
#pragma unroll
        for (int o = 32; o; o >>= 1) s += __shfl_xor(s, o);
        float a = p * (1.f / fmaxf(s, 1e-9f));

        int iters = (deg + 3) >> 2;   // wave-uniform per-group trip count
        int quad = iters >> 2;
        int i = g;
        for (int t4 = 0; t4 < quad; ++t4, i += 16) {
            int s0 = __shfl(sidx, i),     s1 = __shfl(sidx, i + 4);
            int s2 = __shfl(sidx, i + 8), s3 = __shfl(sidx, i + 12);
            float w0 = __shfl(a, i),     w1 = __shfl(a, i + 4);
            float w2 = __shfl(a, i + 8), w3 = __shfl(a, i + 12);
            float2 r0 = *(const float2*)(h + (size_t)s0 * 64 + foff);
            float2 r1 = *(const float2*)(h + (size_t)s1 * 64 + foff);
            float2 r2 = *(const float2*)(h + (size_t)s2 * 64 + foff);
            float2 r3 = *(const float2*)(h + (size_t)s3 * 64 + foff);
#if USE_DOT2
            edge_pair_dot(r0, r1, w0, w1, accv);
            edge_pair_dot(r2, r3, w2, w3, accv);
#else
            edge_one(r0, w0, accv); edge_one(r1, w1, accv);
            edge_one(r2, w2, accv); edge_one(r3, w3, accv);
#endif
        }
        int rem = iters & 3;
        for (int rr2 = 0; rr2 < rem; ++rr2, i += 4) {
            int s0 = __shfl(sidx, i);
            float w0 = __shfl(a, i);
            float2 r0 = *(const float2*)(h + (size_t)s0 * 64 + foff);
            edge_one(r0, w0, accv);
        }
    } else {
        int end = beg + deg;
        float m = -1e30f;
        for (int i = beg + lane; i < end; i += 64) {
            float e = el[csr_src[i]] + ern;
            e = e > 0.f ? e : NEG_SLOPE * e;
            m = fmaxf(m, e);
        }
#pragma unroll
        for (int o = 32; o; o >>= 1) m = fmaxf(m, __shfl_xor(m, o));
        float s = 0.f;
        for (int i = beg + lane; i < end; i += 64) {
            float e = el[csr_src[i]] + ern;
            e = e > 0.f ? e : NEG_SLOPE * e;
            s += __expf(e - m);
        }
#pragma unroll
        for (int o = 32; o; o >>= 1) s += __shfl_xor(s, o);
        float inv = 1.f / fmaxf(s, 1e-9f);
        for (int i = g; i < deg; i += 4) {
            int s0 = csr_src[beg + i];
            float e = el[s0] + ern;
            e = e > 0.f ? e : NEG_SLOPE * e;
            float w0 = __expf(e - m) * inv;
            float2 r0 = *(const float2*)(h + (size_t)s0 * 64 + foff);
            edge_one(r0, w0, accv);
        }
    }

#pragma unroll
    for (int o = 16; o <= 32; o <<= 1) {
        accv.x += __shfl_xor(accv.x, o);
        accv.y += __shfl_xor(accv.y, o);
        accv.z += __shfl_xor(accv.z, o);
        accv.w += __shfl_xor(accv.w, o);
    }
    return accv;
}

// ---------------- fused agg1 + GEMM2 ----------------
// launch_bounds (256,8): round 13 had (256,4) which capped the latency-bound
// gather at 16 waves/CU (occupancy 54%, VALUBusy 46%). LDS 16KB allows 10
// blocks/CU, VGPR 28 allows 8+.

__global__ __launch_bounds__(256, 8) void k_aggemm(
    const __half* __restrict__ h, const float* __restrict__ el,
    const float* __restrict__ er, const float* __restrict__ b1,
    const int* __restrict__ offs, const int* __restrict__ csr_src,
    const float* __restrict__ W2, const float* __restrict__ al2,
    const float* __restrict__ ar2,
    __half* __restrict__ h2, float* __restrict__ el2, float* __restrict__ er2,
    int N) {

    __shared__ float4 SMEM[1024];    // 16KB: A 8KB | W2t 8KB
    char* A  = (char*)SMEM;
    char* Bw = (char*)SMEM + 8192;
    int t = threadIdx.x;
    int w = t >> 6, lane = t & 63, g = lane >> 4, fl = lane & 15;
    int row0 = blockIdx.x * 64;

    // stage W2^T (64x64 f32 -> f16, swizzled)
    for (int i = t; i < 1024; i += 256) {
        int k = i >> 4, c4 = (i & 15) * 4;
        float4 v = *(const float4*)(W2 + k * 64 + c4);
        int kb = k * 2;
        *(__half*)(Bw + (c4 + 0) * 128 + (kb ^ (((c4 + 0) & 7) << 4))) = __float2half(v.x);
        *(__half*)(Bw + (c4 + 1) * 128 + (kb ^ (((c4 + 1) & 7) << 4))) = __float2half(v.y);
        *(__half*)(Bw + (c4 + 2) * 128 + (kb ^ (((c4 + 2) & 7) << 4))) = __float2half(v.z);
        *(__half*)(Bw + (c4 + 3) * 128 + (kb ^ (((c4 + 3) & 7) << 4))) = __float2half(v.w);
    }

    // ---- agg phase: wave w handles rows w*16 .. w*16+15 ----
    const size_t foff = 4 * (size_t)fl;
    float4 bv = *(const float4*)(b1 + foff);   // used by lanes 0..15
    for (int j = 0; j < 16; ++j) {
        int r = w * 16 + j;
        int n = row0 + r;
        int beg = 0, deg = 0;
        float ern = 0.f;
        if (n < N) {
            beg = offs[n];
            deg = offs[n + 1] - beg;
            ern = er[n];
        }
        float4 accv = agg_node(h, el, ern, csr_src, beg, deg, lane, g, foff);
        if (lane < 16) {
            float ox = fmaxf(accv.x + bv.x, 0.f);
            float oy = fmaxf(accv.y + bv.y, 0.f);
            float oz = fmaxf(accv.z + bv.z, 0.f);
            float ow = fmaxf(accv.w + bv.w, 0.f);
            __half2 h01 = __floats2half2_rn(ox, oy);
            __half2 h23 = __floats2half2_rn(oz, ow);
            float2 pk;
            pk.x = __builtin_bit_cast(float, h01);
            pk.y = __builtin_bit_cast(float, h23);
            *(float2*)(A + r * 128 + ((int)(fl * 8) ^ ((r & 7) << 4))) = pk;
        }
    }
    __syncthreads();

    // ---- MFMA phase (gemm2) ----
    int c = fl;
    int swz = (c & 7) << 4;
    const char* Ar = A + (w * 16 + c) * 128;

    f32x4 acc[4];
#pragma unroll
    for (int t2 = 0; t2 < 4; ++t2) acc[t2] = (f32x4){0.f, 0.f, 0.f, 0.f};
#pragma unroll
    for (int kk = 0; kk < 2; ++kk) {
        int kb = kk * 64 + g * 16;
        f16x8 av = *(const f16x8*)(Ar + (kb ^ swz));
#pragma unroll
        for (int t2 = 0; t2 < 4; ++t2) {
            f16x8 bvf = *(const f16x8*)(Bw + (t2 * 16 + c) * 128 + (kb ^ swz));
            acc[t2] = __builtin_amdgcn_mfma_f32_16x16x32_f16(av, bvf, acc[t2], 0, 0, 0);
        }
    }

    float alv[4], arv[4];
#pragma unroll
    for (int t2 = 0; t2 < 4; ++t2) { alv[t2] = al2[t2 * 16 + c]; arv[t2] = ar2[t2 * 16 + c]; }
#pragma unroll
    for (int r = 0; r < 4; ++r) {
        float e1 = 0.f, e2 = 0.f;
#pragma unroll
        for (int t2 = 0; t2 < 4; ++t2) {
            e1 = fmaf(acc[t2][r], alv[t2], e1);
            e2 = fmaf(acc[t2][r], arv[t2], e2);
        }
#pragma unroll
        for (int o = 1; o < 16; o <<= 1) { e1 += __shfl_xor(e1, o); e2 += __shfl_xor(e2, o); }
        int row = row0 + w * 16 + 4 * g + r;
        if (row < N) {
            if (c == 0) { el2[row] = e1; er2[row] = e2; }
#pragma unroll
            for (int t2 = 0; t2 < 4; ++t2)
                h2[(size_t)row * 64 + t2 * 16 + c] = __float2half(acc[t2][r]);
        }
    }
}

// ---------------- layer-2 agg (writes fp32 out) ----------------

__global__ __launch_bounds__(256, 8) void k_agg2(const __half* __restrict__ h,
                                                 const float* __restrict__ el,
                                                 const float* __restrict__ er,
                                                 const float* __restrict__ b,
                                                 const int* __restrict__ offs,
                                                 const int* __restrict__ csr_src,
                                                 float* __restrict__ out, int N) {
    int wave = threadIdx.x >> 6, lane = threadIdx.x & 63;
    int n = blockIdx.x * 4 + wave;
    if (n >= N) return;

    int beg = offs[n], deg = offs[n + 1] - beg;
    int g = lane >> 4, fl = lane & 15;
    const size_t foff = 4 * (size_t)fl;

    float4 accv = agg_node(h, el, er[n], csr_src, beg, deg, lane, g, foff);

    if (lane < 16) {
        float4 bv = *(const float4*)(b + foff);
        *(float4*)(out + (size_t)n * 64 + foff) =
            make_float4(accv.x + bv.x, accv.y + bv.y, accv.z + bv.z, accv.w + bv.w);
    }
}

// ---------------- launch ----------------

extern "C" void kernel_launch(void* const* d_in, const int* in_sizes, int n_in,
                              void* d_out, int out_size, void* d_ws, size_t ws_size,
                              hipStream_t stream) {
    const float* x   = (const float*)d_in[0];
    const int*   src = (const int*)d_in[1];
    const int*   dst = (const int*)d_in[2];
    const float* W1  = (const float*)d_in[3];
    const float* al1 = (const float*)d_in[4];
    const float* ar1 = (const float*)d_in[5];
    const float* b1  = (const float*)d_in[6];
    const float* W2  = (const float*)d_in[7];
    const float* al2 = (const float*)d_in[8];
    const float* ar2 = (const float*)d_in[9];
    const float* b2  = (const float*)d_in[10];
    float* out = (float*)d_out;

    const int N = NNODES;
    const int E = in_sizes[1];

    __half* h    = (__half*)d_ws;                      // 12.8MB (layer-1 h)
    __half* h2   = h + (size_t)N * 64;                 // 12.8MB (layer-2 h)
    int*    be   = (int*)(h2 + (size_t)N * 64);        // NBK*BCAP (6.9MB)
    int*    csr  = be + (size_t)NBK * BCAP;            // E (6.4MB)
    float*  el   = (float*)(csr + E);                  // N
    float*  er   = el + N;                             // N
    float*  el2  = er + N;                             // N
    float*  er2  = el2 + N;                            // N
    int*    offs = (int*)(er2 + N);                    // N+1
    int*    gcur = offs + N + 1;                       // NBK

    int nbBin = (E + B1 - 1) / B1;            // 391
    int nbG   = (N + 63) / 64;                // 1563
    int nbR   = (N + 3) / 4;                  // 25000

    k_init<<<1, 64, 0, stream>>>(gcur, offs, N, E);
    // bin (391 blocks) fused with layer-1 MFMA GEMM (1563 blocks) - independent
    k_gemm1b<<<nbBin + nbG, 256, 0, stream>>>(x, W1, al1, ar1, h, el, er, N,
                                              nbBin, src, dst, gcur, be, E);
    k_offs<<<NBK, 256, 0, stream>>>(be, gcur, offs, N);
    k_scat<<<8 * SLSTRIDE, 256, 0, stream>>>(be, gcur, offs, csr, N);
    // fused: agg layer-1 + GEMM2 (hmid stays in LDS)
    k_aggemm<<<nbG, 256, 0, stream>>>(h, el, er, b1, offs, csr,
                                      W2, al2, ar2, h2, el2, er2, N);
    k_agg2<<<nbR, 256, 0, stream>>>(h2, el2, er2, b2, offs, csr, out, N);
}